// Round 14
// baseline (177.035 us; speedup 1.0000x reference)
//
#include <hip/hip_runtime.h>
#include <cstdint>
#include <cstddef>

#define SEQ 2048
#define BATCH 4
#define KVB 64
#define NT (SEQ / KVB)

typedef __attribute__((ext_vector_type(8))) unsigned short u16x8;
typedef __attribute__((ext_vector_type(8))) __bf16 bf16x8;
typedef __attribute__((ext_vector_type(4))) float f32x4;
typedef __attribute__((ext_vector_type(4))) unsigned short u16x4;

#if defined(__has_builtin)
#if __has_builtin(__builtin_amdgcn_exp2f)
#define EXP2(x) __builtin_amdgcn_exp2f(x)
#else
#define EXP2(x) exp2f(x)
#endif
#else
#define EXP2(x) exp2f(x)
#endif

static __device__ __forceinline__ unsigned short f2bf(float f) {
  unsigned u = __builtin_bit_cast(unsigned, f);
  u += 0x7fffu + ((u >> 16) & 1u);   // round-to-nearest-even
  return (unsigned short)(u >> 16);
}

static __device__ __forceinline__ f32x4 mfma16(u16x8 a, u16x8 b, f32x4 c) {
  return __builtin_amdgcn_mfma_f32_16x16x32_bf16(
      __builtin_bit_cast(bf16x8, a), __builtin_bit_cast(bf16x8, b), c, 0, 0, 0);
}

static __device__ __forceinline__ f32x4 mfma16b(u16x8 a, bf16x8 b, f32x4 c) {
  return __builtin_amdgcn_mfma_f32_16x16x32_bf16(
      __builtin_bit_cast(bf16x8, a), b, c, 0, 0, 0);
}

static __device__ __forceinline__ void gl_lds16(const void* g, void* l) {
  __builtin_amdgcn_global_load_lds(
      (const __attribute__((address_space(1))) void*)g,
      (__attribute__((address_space(3))) void*)l, 16, 0, 0);
}

// ---------------- x fp32 -> bf16 ----------------
__global__ __launch_bounds__(256) void k_conv_x(const float* __restrict__ x,
                                                unsigned short* __restrict__ xb) {
  int i = (blockIdx.x * 256 + threadIdx.x) * 8;
  f32x4 a = *reinterpret_cast<const f32x4*>(x + i);
  f32x4 b = *reinterpret_cast<const f32x4*>(x + i + 4);
  u16x8 v;
  v[0] = f2bf(a[0]); v[1] = f2bf(a[1]); v[2] = f2bf(a[2]); v[3] = f2bf(a[3]);
  v[4] = f2bf(b[0]); v[5] = f2bf(b[1]); v[6] = f2bf(b[2]); v[7] = f2bf(b[3]);
  *reinterpret_cast<u16x8*>(xb + i) = v;
}

// ---------------- W [k][n] fp32 -> Wt [n][k] bf16 ----------------
__global__ __launch_bounds__(256) void k_conv_w(const float* __restrict__ Wq,
                                                const float* __restrict__ Wk,
                                                const float* __restrict__ Wv,
                                                unsigned short* __restrict__ wt) {
  const float* W = (blockIdx.z == 0) ? Wq : (blockIdx.z == 1) ? Wk : Wv;
  unsigned short* dst = wt + (size_t)blockIdx.z * 1024 * 1024;
  __shared__ float tile[32][33];
  int n0 = blockIdx.x * 32, k0 = blockIdx.y * 32;
  int tx = threadIdx.x, ty = threadIdx.y;
#pragma unroll
  for (int i = 0; i < 4; i++) {
    int k = ty + i * 8;
    tile[k][tx] = W[(size_t)(k0 + k) * 1024 + n0 + tx];
  }
  __syncthreads();
#pragma unroll
  for (int i = 0; i < 4; i++) {
    int n = ty + i * 8;
    dst[(size_t)(n0 + n) * 1024 + k0 + tx] = f2bf(tile[tx][n]);
  }
}

// ---------------- QKV projection GEMM (wide-acc 256x128) ----------------
// z=0 -> Q [B,H,S,64] * (log2e/32); z=1 -> K [B,H,S,64]
// z=2 -> Vt [B,H,64,S] with sigma-permuted s within each 32-block.
// Tile 256(M)x128(N), 4 waves, wave = 64 rows x 128 cols: acc[4][8],
// 12 b128 LDS reads per 32 MFMAs (vs 8 per 16) -> LDS-read pipe unbound.
// XCD grid: 768 = 8 xcd x (3 z x 4 mg x 8 n); xcd owns m-tiles %8==xcd.
// 3-buffer pipeline, counted vmcnt(6), raw barriers; swizzle c^=(row>>1)&3.
__global__ __launch_bounds__(256) void k_qkv_gemm(
    const unsigned short* __restrict__ xb, const unsigned short* __restrict__ wt,
    const float* __restrict__ bq, const float* __restrict__ bk,
    const float* __restrict__ bv,
    unsigned short* __restrict__ qb, unsigned short* __restrict__ kb,
    unsigned short* __restrict__ vt) {
  __shared__ unsigned short Ah[3][256 * 32];
  __shared__ unsigned short Bh[3][128 * 32];
  const int tid = threadIdx.x;
  const int lane = tid & 63, wid = tid >> 6;
  const int ln = lane & 15, g = lane >> 4;
  const int dd = blockIdx.x;
  const int xcd = dd & 7, j = dd >> 3;       // j in [0,96)
  const int z = j >> 5, kk = j & 31;
  const int m0 = ((kk >> 3) * 8 + xcd) * 256;
  const int n0 = (kk & 7) * 128;
  const unsigned short* Bt = wt + (size_t)z * 1024 * 1024;

  f32x4 acc[4][8];
#pragma unroll
  for (int i = 0; i < 4; i++)
#pragma unroll
    for (int jj = 0; jj < 8; jj++) acc[i][jj] = f32x4{0.f, 0.f, 0.f, 0.f};

  const int rA0 = tid >> 2, cA0 = tid & 3;
  const int swA = (cA0 ^ ((rA0 >> 1) & 3)) << 3;  // pre-swizzled source chunk
  // rows +64/+128/+192 keep (row>>1)&3 invariant -> same swizzle

  const unsigned short* gA0 = xb + (size_t)(m0 + rA0) * 1024 + swA;
  const unsigned short* gB0 = Bt + (size_t)(n0 + rA0) * 1024 + swA;

#define GSTAGE(bb, k0)                                                \
  do {                                                                \
    gl_lds16(gA0 + (k0), &Ah[bb][wid * 512]);                         \
    gl_lds16(gA0 + 64 * 1024 + (k0), &Ah[bb][2048 + wid * 512]);      \
    gl_lds16(gA0 + 128 * 1024 + (k0), &Ah[bb][4096 + wid * 512]);     \
    gl_lds16(gA0 + 192 * 1024 + (k0), &Ah[bb][6144 + wid * 512]);     \
    gl_lds16(gB0 + (k0), &Bh[bb][wid * 512]);                         \
    gl_lds16(gB0 + 64 * 1024 + (k0), &Bh[bb][2048 + wid * 512]);      \
  } while (0)

  const int fsw = (g ^ ((ln >> 1) & 3)) << 3;     // conflict-free frag read

#define GCOMPUTE(bb)                                                       \
  do {                                                                     \
    u16x8 af[4];                                                           \
    _Pragma("unroll") for (int mi = 0; mi < 4; mi++)                       \
      af[mi] = *reinterpret_cast<const u16x8*>(                            \
          &Ah[bb][(wid * 64 + mi * 16 + ln) * 32 + fsw]);                  \
    __builtin_amdgcn_s_setprio(1);                                         \
    _Pragma("unroll") for (int ni = 0; ni < 8; ni++) {                     \
      u16x8 bv = *reinterpret_cast<const u16x8*>(                          \
          &Bh[bb][(ni * 16 + ln) * 32 + fsw]);                             \
      _Pragma("unroll") for (int mi = 0; mi < 4; mi++)                     \
        acc[mi][ni] = mfma16(af[mi], bv, acc[mi][ni]);                     \
    }                                                                      \
    __builtin_amdgcn_s_setprio(0);                                         \
  } while (0)

  // prologue: 2 tiles in flight
  GSTAGE(0, 0);
  GSTAGE(1, 32);
  asm volatile("s_waitcnt vmcnt(6)" ::: "memory");   // tile 0 landed
  __builtin_amdgcn_s_barrier();

  // main: 32 K-steps of 32; loads for t+1, t+2 stay in flight across barrier
  for (int t = 0; t < 30; t++) {
    GCOMPUTE(t % 3);
    GSTAGE((t + 2) % 3, (t + 2) * 32);
    asm volatile("s_waitcnt vmcnt(6)" ::: "memory"); // tile t+1 landed
    __builtin_amdgcn_s_barrier();
  }
  GCOMPUTE(0);                                       // tile 30
  asm volatile("s_waitcnt vmcnt(0)" ::: "memory");   // tile 31 landed
  __builtin_amdgcn_s_barrier();
  GCOMPUTE(1);                                       // tile 31

  const float* bias = (z == 0) ? bq : (z == 1) ? bk : bv;
#pragma unroll
  for (int ni = 0; ni < 8; ni++) {
    int n = n0 + ni * 16 + ln;
    float bb = bias[n];
    int h = n >> 6, d = n & 63;
#pragma unroll
    for (int mi = 0; mi < 4; mi++) {
      int mb = m0 + wid * 64 + mi * 16 + 4 * g;
      int b = mb >> 11, s = mb & 2047;
      if (z == 2) {
        u16x4 pv;
#pragma unroll
        for (int i = 0; i < 4; i++) pv[i] = f2bf(acc[mi][ni][i] + bb);
        int s4 = s >> 2;
        int u = s4 & 7, blk = s4 >> 3;
        int nu = ((u & 3) << 1) | (u >> 2);
        int sp = ((blk << 3) | nu) << 2;
        *reinterpret_cast<u16x4*>(
            &vt[((size_t)((b * 16 + h) * 64 + d)) * 2048 + sp]) = pv;
      } else {
        unsigned short* dst = (z == 0) ? qb : kb;
        float sc = (z == 0) ? 0.0450842200f : 1.0f;  // 1/32 * log2(e)
#pragma unroll
        for (int i = 0; i < 4; i++) {
          dst[((size_t)((b * 16 + h) * 2048) + (s + i)) * 64 + d] =
              f2bf((acc[mi][ni][i] + bb) * sc);
        }
      }
    }
  }
#undef GSTAGE
#undef GCOMPUTE
}

// ---------------- flash attention (R9 structure, proven) ----------------
// 8 waves/block (QBLK=256), KVB=64, 3-buffer pipeline (48 KB LDS),
// STAGE-first body with counted vmcnt(2) + raw barriers (no drain-0).
// Swapped QK^T; static-max softmax p=exp2(score); l-sum via ones-row MFMA;
// V sigma-permuted in global so PV A-fragments are single b128 LDS reads.
__global__ __launch_bounds__(512) void k_attn(
    const unsigned short* __restrict__ qb, const unsigned short* __restrict__ kb,
    const unsigned short* __restrict__ vt, float* __restrict__ out) {
  __shared__ unsigned short Kl[3][KVB * 64];  // [kv][d], 16B-chunk XOR-swizzled
  __shared__ unsigned short Vl[3][64 * KVB];  // [d][kv_sigma], XOR-swizzled
  const int tid = threadIdx.x;
  const int lane = tid & 63, wid = tid >> 6;
  const int ln = lane & 15, g = lane >> 4;
  const int flat = blockIdx.x;
  const int bh = flat & 63, qidx = flat >> 6;
  const int b = bh >> 4, h = bh & 15;
  const int q0 = qidx * 256 + wid * 32;
  const unsigned short* Qp = qb + (size_t)bh * SEQ * 64;
  const unsigned short* Kp = kb + (size_t)bh * SEQ * 64;
  const unsigned short* Vp = vt + (size_t)bh * 64 * SEQ;

  // staging source (per-thread, 16B-chunk XOR swizzle folded into global addr)
  const int kr0 = tid >> 3;
  const int psw = ((tid & 7) ^ (kr0 & 7)) << 3;
  const unsigned short* srcK0 = Kp + (size_t)kr0 * 64 + psw;
  const unsigned short* srcV0 = Vp + (size_t)kr0 * SEQ + psw;

#define STAGE(bb, tt)                                                     \
  do {                                                                    \
    gl_lds16(srcK0 + (size_t)(tt) * (KVB * 64), &Kl[bb][wid * 512]);      \
    gl_lds16(srcV0 + (size_t)(tt) * KVB, &Vl[bb][wid * 512]);             \
  } while (0)

  // Q fragments (one-time)
  u16x8 qf[2][2];
#pragma unroll
  for (int qt = 0; qt < 2; qt++)
#pragma unroll
    for (int dc = 0; dc < 2; dc++)
      qf[qt][dc] = *reinterpret_cast<const u16x8*>(
          &Qp[(size_t)(q0 + qt * 16 + ln) * 64 + dc * 32 + g * 8]);

  f32x4 o[4][2];
#pragma unroll
  for (int dt = 0; dt < 4; dt++)
#pragma unroll
    for (int qt = 0; qt < 2; qt++) o[dt][qt] = f32x4{0.f, 0.f, 0.f, 0.f};
  f32x4 lsum[2] = {f32x4{0.f, 0.f, 0.f, 0.f}, f32x4{0.f, 0.f, 0.f, 0.f}};

  u16x8 ones;
#pragma unroll
  for (int i = 0; i < 8; i++) ones[i] = 0x3F80;  // bf16 1.0

  // swizzled read offsets (elems)
  const int lm = ln & 7;
  const int ksw0 = (g ^ lm) << 3;
  const int ksw1 = ((4 + g) ^ lm) << 3;
  const int vsw0 = (g ^ lm) << 3;           // ks=0: chunk g
  const int vsw1 = ((4 + g) ^ lm) << 3;     // ks=1: chunk 4+g

#define ACOMPUTE(bi)                                                          \
  do {                                                                        \
    const unsigned short* Kb = Kl[bi];                                        \
    const unsigned short* Vb = Vl[bi];                                        \
    u16x8 kf[4][2];                                                           \
    _Pragma("unroll") for (int kt = 0; kt < 4; kt++) {                        \
      int rb = (kt * 16 + ln) * 64;                                           \
      kf[kt][0] = *reinterpret_cast<const u16x8*>(&Kb[rb + ksw0]);            \
      kf[kt][1] = *reinterpret_cast<const u16x8*>(&Kb[rb + ksw1]);            \
    }                                                                         \
    f32x4 st[2][4];                                                           \
    __builtin_amdgcn_s_setprio(1);                                            \
    _Pragma("unroll") for (int qt = 0; qt < 2; qt++)                          \
    _Pragma("unroll") for (int kt = 0; kt < 4; kt++) {                        \
      f32x4 c = f32x4{0.f, 0.f, 0.f, 0.f};                                    \
      c = mfma16(kf[kt][0], qf[qt][0], c);                                    \
      c = mfma16(kf[kt][1], qf[qt][1], c);                                    \
      st[qt][kt] = c;                                                         \
    }                                                                         \
    __builtin_amdgcn_s_setprio(0);                                            \
    _Pragma("unroll") for (int qt = 0; qt < 2; qt++)                          \
    _Pragma("unroll") for (int kt = 0; kt < 4; kt++)                          \
    _Pragma("unroll") for (int i = 0; i < 4; i++)                             \
      st[qt][kt][i] = EXP2(st[qt][kt][i]);                                    \
    bf16x8 pb[2][2];                                                          \
    _Pragma("unroll") for (int qt = 0; qt < 2; qt++)                          \
    _Pragma("unroll") for (int ks = 0; ks < 2; ks++)                          \
    _Pragma("unroll") for (int i = 0; i < 4; i++) {                           \
      pb[qt][ks][i] = (__bf16)st[qt][2 * ks][i];                              \
      pb[qt][ks][4 + i] = (__bf16)st[qt][2 * ks + 1][i];                      \
    }                                                                         \
    __builtin_amdgcn_s_setprio(1);                                            \
    _Pragma("unroll") for (int dt = 0; dt < 4; dt++) {                        \
      int rb = (dt * 16 + ln) * 64;                                           \
      u16x8 vf0 = *reinterpret_cast<const u16x8*>(&Vb[rb + vsw0]);            \
      o[dt][0] = mfma16b(vf0, pb[0][0], o[dt][0]);                            \
      o[dt][1] = mfma16b(vf0, pb[1][0], o[dt][1]);                            \
      u16x8 vf1 = *reinterpret_cast<const u16x8*>(&Vb[rb + vsw1]);            \
      o[dt][0] = mfma16b(vf1, pb[0][1], o[dt][0]);                            \
      o[dt][1] = mfma16b(vf1, pb[1][1], o[dt][1]);                            \
    }                                                                         \
    _Pragma("unroll") for (int ks = 0; ks < 2; ks++) {                        \
      lsum[0] = mfma16b(ones, pb[0][ks], lsum[0]);                            \
      lsum[1] = mfma16b(ones, pb[1][ks], lsum[1]);                            \
    }                                                                         \
    __builtin_amdgcn_s_setprio(0);                                            \
  } while (0)

  // prologue: 2 tiles in flight
  STAGE(0, 0);
  STAGE(1, 1);
  asm volatile("s_waitcnt vmcnt(2)" ::: "memory");   // tile 0 landed
  __builtin_amdgcn_s_barrier();

  for (int t = 0; t < NT - 2; t++) {
    STAGE((t + 2) % 3, t + 2);
    ACOMPUTE(t % 3);
    asm volatile("s_waitcnt vmcnt(2)" ::: "memory"); // tile t+1 landed
    __builtin_amdgcn_s_barrier();
  }
  ACOMPUTE((NT - 2) % 3);                            // tile 30
  asm volatile("s_waitcnt vmcnt(0)" ::: "memory");   // tile 31 landed
  __builtin_amdgcn_s_barrier();
  ACOMPUTE((NT - 1) % 3);                            // tile 31

  float inv[2] = {1.f / lsum[0][0], 1.f / lsum[1][0]};

#pragma unroll
  for (int qt = 0; qt < 2; qt++) {
    int q = q0 + qt * 16 + ln;
#pragma unroll
    for (int dt = 0; dt < 4; dt++) {
      f32x4 r;
#pragma unroll
      for (int i = 0; i < 4; i++) r[i] = o[dt][qt][i] * inv[qt];
      *reinterpret_cast<f32x4*>(
          &out[((size_t)(b * SEQ + q)) * 1024 + h * 64 + dt * 16 + 4 * g]) = r;
    }
  }
#undef STAGE
#undef ACOMPUTE
}

// ---------------- launch ----------------
extern "C" void kernel_launch(void* const* d_in, const int* in_sizes, int n_in,
                              void* d_out, int out_size, void* d_ws, size_t ws_size,
                              hipStream_t stream) {
  (void)in_sizes; (void)n_in; (void)out_size;
  const float* x  = (const float*)d_in[0];
  const float* Wq = (const float*)d_in[1];
  const float* bq = (const float*)d_in[2];
  const float* Wk = (const float*)d_in[3];
  const float* bk = (const float*)d_in[4];
  const float* Wv = (const float*)d_in[5];
  const float* bv = (const float*)d_in[6];
  float* out = (float*)d_out;

  char* ws = (char*)d_ws;
  // layout (bytes): xb 16MB | wt 6MB | q 16MB | k 16MB | vt 16MB  = 73400320
  if (ws_size < 73400320u) return;
  unsigned short* xb    = (unsigned short*)(ws);
  unsigned short* wt    = (unsigned short*)(ws + 16777216);
  unsigned short* qbuf  = (unsigned short*)(ws + 23068672);
  unsigned short* kbuf  = (unsigned short*)(ws + 39845888);
  unsigned short* vtbuf = (unsigned short*)(ws + 56623104);

  k_conv_x<<<4096, 256, 0, stream>>>(x, xb);
  k_conv_w<<<dim3(32, 32, 3), dim3(32, 8), 0, stream>>>(Wq, Wk, Wv, wt);
  k_qkv_gemm<<<dim3(768), 256, 0, stream>>>(xb, wt, bq, bk, bv,
                                            qbuf, kbuf, vtbuf);
  k_attn<<<dim3(512), dim3(512), 0, stream>>>(qbuf, kbuf, vtbuf, out);
}

// Round 15
// 149.193 us; speedup vs baseline: 1.1866x; 1.1866x over previous
//
#include <hip/hip_runtime.h>
#include <cstdint>
#include <cstddef>

#define SEQ 2048
#define BATCH 4
#define KVB 64
#define NT (SEQ / KVB)

typedef __attribute__((ext_vector_type(8))) unsigned short u16x8;
typedef __attribute__((ext_vector_type(8))) __bf16 bf16x8;
typedef __attribute__((ext_vector_type(4))) float f32x4;
typedef __attribute__((ext_vector_type(4))) unsigned short u16x4;

#if defined(__has_builtin)
#if __has_builtin(__builtin_amdgcn_exp2f)
#define EXP2(x) __builtin_amdgcn_exp2f(x)
#else
#define EXP2(x) exp2f(x)
#endif
#else
#define EXP2(x) exp2f(x)
#endif

static __device__ __forceinline__ unsigned short f2bf(float f) {
  unsigned u = __builtin_bit_cast(unsigned, f);
  u += 0x7fffu + ((u >> 16) & 1u);   // round-to-nearest-even
  return (unsigned short)(u >> 16);
}

static __device__ __forceinline__ f32x4 mfma16(u16x8 a, u16x8 b, f32x4 c) {
  return __builtin_amdgcn_mfma_f32_16x16x32_bf16(
      __builtin_bit_cast(bf16x8, a), __builtin_bit_cast(bf16x8, b), c, 0, 0, 0);
}

static __device__ __forceinline__ f32x4 mfma16b(u16x8 a, bf16x8 b, f32x4 c) {
  return __builtin_amdgcn_mfma_f32_16x16x32_bf16(
      __builtin_bit_cast(bf16x8, a), b, c, 0, 0, 0);
}

static __device__ __forceinline__ void gl_lds16(const void* g, void* l) {
  __builtin_amdgcn_global_load_lds(
      (const __attribute__((address_space(1))) void*)g,
      (__attribute__((address_space(3))) void*)l, 16, 0, 0);
}

// ---------------- x fp32 -> bf16 ----------------
__global__ __launch_bounds__(256) void k_conv_x(const float* __restrict__ x,
                                                unsigned short* __restrict__ xb) {
  int i = (blockIdx.x * 256 + threadIdx.x) * 8;
  f32x4 a = *reinterpret_cast<const f32x4*>(x + i);
  f32x4 b = *reinterpret_cast<const f32x4*>(x + i + 4);
  u16x8 v;
  v[0] = f2bf(a[0]); v[1] = f2bf(a[1]); v[2] = f2bf(a[2]); v[3] = f2bf(a[3]);
  v[4] = f2bf(b[0]); v[5] = f2bf(b[1]); v[6] = f2bf(b[2]); v[7] = f2bf(b[3]);
  *reinterpret_cast<u16x8*>(xb + i) = v;
}

// ---------------- W [k][n] fp32 -> Wt [n][k] bf16 ----------------
__global__ __launch_bounds__(256) void k_conv_w(const float* __restrict__ Wq,
                                                const float* __restrict__ Wk,
                                                const float* __restrict__ Wv,
                                                unsigned short* __restrict__ wt) {
  const float* W = (blockIdx.z == 0) ? Wq : (blockIdx.z == 1) ? Wk : Wv;
  unsigned short* dst = wt + (size_t)blockIdx.z * 1024 * 1024;
  __shared__ float tile[32][33];
  int n0 = blockIdx.x * 32, k0 = blockIdx.y * 32;
  int tx = threadIdx.x, ty = threadIdx.y;
#pragma unroll
  for (int i = 0; i < 4; i++) {
    int k = ty + i * 8;
    tile[k][tx] = W[(size_t)(k0 + k) * 1024 + n0 + tx];
  }
  __syncthreads();
#pragma unroll
  for (int i = 0; i < 4; i++) {
    int n = ty + i * 8;
    dst[(size_t)(n0 + n) * 1024 + k0 + tx] = f2bf(tile[tx][n]);
  }
}

// ---------------- QKV projection GEMM (R8 structure, proven) ----------------
// z=0 -> Q [B,H,S,64] * (log2e/32); z=1 -> K [B,H,S,64]
// z=2 -> Vt [B,H,64,S] with sigma-permuted s within each 32-block.
// XCD-aware flat grid, per-XCD order (n slowest, mg, z fastest): the three
// z's of one (m,n) tile run back-to-back -> A-tile L2-hot; per-XCD A slice
// (2MB) stays L2-resident -> staging loads L2-class, vmcnt wait covered.
// 3-buffer LDS pipeline, counted vmcnt(4) across RAW barriers (no drain-0
// in main loop); conflict-free swizzle c ^= (row>>1)&3.
__global__ __launch_bounds__(256) void k_qkv_gemm(
    const unsigned short* __restrict__ xb, const unsigned short* __restrict__ wt,
    const float* __restrict__ bq, const float* __restrict__ bk,
    const float* __restrict__ bv,
    unsigned short* __restrict__ qb, unsigned short* __restrict__ kb,
    unsigned short* __restrict__ vt) {
  __shared__ unsigned short Ah[3][128 * 32];
  __shared__ unsigned short Bh[3][128 * 32];
  const int tid = threadIdx.x;
  const int lane = tid & 63, wid = tid >> 6;
  const int ln = lane & 15, g = lane >> 4;
  const int wr = wid >> 1, wc = wid & 1;
  // flat 1536 = 8 xcd x 192; per-XCD j = n*24 + mg*3 + z (z fastest)
  const int dd = blockIdx.x;
  const int xcd = dd & 7, j = dd >> 3;        // j in [0,192)
  const int n_idx = j / 24;                   // [0,8) slowest
  const int r = j - n_idx * 24;
  const int mg = r / 3;                       // [0,8)
  const int z = r - mg * 3;                   // [0,3) fastest
  const int m0 = ((mg << 3) | xcd) * 128;
  const int n0 = n_idx * 128;
  const unsigned short* Bt = wt + (size_t)z * 1024 * 1024;

  f32x4 acc[4][4];
#pragma unroll
  for (int i = 0; i < 4; i++)
#pragma unroll
    for (int jj = 0; jj < 4; jj++) acc[i][jj] = f32x4{0.f, 0.f, 0.f, 0.f};

  const int rA0 = tid >> 2, cA0 = tid & 3;
  const int swA = (cA0 ^ ((rA0 >> 1) & 3)) << 3;  // pre-swizzled source chunk
  const int rA1 = rA0 + 64;                       // (rA1>>1)&3 == (rA0>>1)&3

  const unsigned short* gA0 = xb + (size_t)(m0 + rA0) * 1024 + swA;
  const unsigned short* gA1 = xb + (size_t)(m0 + rA1) * 1024 + swA;
  const unsigned short* gB0 = Bt + (size_t)(n0 + rA0) * 1024 + swA;
  const unsigned short* gB1 = Bt + (size_t)(n0 + rA1) * 1024 + swA;

#define GSTAGE(bb, k0)                                          \
  do {                                                          \
    gl_lds16(gA0 + (k0), &Ah[bb][wid * 512]);                   \
    gl_lds16(gA1 + (k0), &Ah[bb][2048 + wid * 512]);            \
    gl_lds16(gB0 + (k0), &Bh[bb][wid * 512]);                   \
    gl_lds16(gB1 + (k0), &Bh[bb][2048 + wid * 512]);            \
  } while (0)

  const int fsw = (g ^ ((ln >> 1) & 3)) << 3;     // conflict-free frag read

#define GCOMPUTE(bb)                                                       \
  do {                                                                     \
    u16x8 af[4], bfv[4];                                                   \
    _Pragma("unroll") for (int mi = 0; mi < 4; mi++)                       \
      af[mi] = *reinterpret_cast<const u16x8*>(                            \
          &Ah[bb][(wr * 64 + mi * 16 + ln) * 32 + fsw]);                   \
    _Pragma("unroll") for (int ni = 0; ni < 4; ni++)                       \
      bfv[ni] = *reinterpret_cast<const u16x8*>(                           \
          &Bh[bb][(wc * 64 + ni * 16 + ln) * 32 + fsw]);                   \
    __builtin_amdgcn_s_setprio(1);                                         \
    _Pragma("unroll") for (int mi = 0; mi < 4; mi++)                       \
    _Pragma("unroll") for (int ni = 0; ni < 4; ni++)                       \
      acc[mi][ni] = mfma16(af[mi], bfv[ni], acc[mi][ni]);                  \
    __builtin_amdgcn_s_setprio(0);                                         \
  } while (0)

  // prologue: 2 tiles in flight
  GSTAGE(0, 0);
  GSTAGE(1, 32);
  asm volatile("s_waitcnt vmcnt(4)" ::: "memory");   // tile 0 landed
  __builtin_amdgcn_s_barrier();

  // main: 32 K-steps of 32; loads for t+1, t+2 stay in flight across barrier
  for (int t = 0; t < 30; t++) {
    GCOMPUTE(t % 3);
    GSTAGE((t + 2) % 3, (t + 2) * 32);
    asm volatile("s_waitcnt vmcnt(4)" ::: "memory"); // tile t+1 landed
    __builtin_amdgcn_s_barrier();
  }
  GCOMPUTE(0);                                       // tile 30
  asm volatile("s_waitcnt vmcnt(0)" ::: "memory");   // tile 31 landed
  __builtin_amdgcn_s_barrier();
  GCOMPUTE(1);                                       // tile 31

  const float* bias = (z == 0) ? bq : (z == 1) ? bk : bv;
#pragma unroll
  for (int ni = 0; ni < 4; ni++) {
    int n = n0 + wc * 64 + ni * 16 + ln;
    float bb = bias[n];
    int h = n >> 6, d = n & 63;
#pragma unroll
    for (int mi = 0; mi < 4; mi++) {
      int mb = m0 + wr * 64 + mi * 16 + 4 * g;
      int b = mb >> 11, s = mb & 2047;
      if (z == 2) {
        u16x4 pv;
#pragma unroll
        for (int i = 0; i < 4; i++) pv[i] = f2bf(acc[mi][ni][i] + bb);
        int s4 = s >> 2;
        int u = s4 & 7, blk = s4 >> 3;
        int nu = ((u & 3) << 1) | (u >> 2);
        int sp = ((blk << 3) | nu) << 2;
        *reinterpret_cast<u16x4*>(
            &vt[((size_t)((b * 16 + h) * 64 + d)) * 2048 + sp]) = pv;
      } else {
        unsigned short* dst = (z == 0) ? qb : kb;
        float sc = (z == 0) ? 0.0450842200f : 1.0f;  // 1/32 * log2(e)
#pragma unroll
        for (int i = 0; i < 4; i++) {
          dst[((size_t)((b * 16 + h) * 2048) + (s + i)) * 64 + d] =
              f2bf((acc[mi][ni][i] + bb) * sc);
        }
      }
    }
  }
#undef GSTAGE
#undef GCOMPUTE
}

// ---------------- flash attention (R9 structure, proven) ----------------
// 8 waves/block (QBLK=256), KVB=64, 3-buffer pipeline (48 KB LDS),
// STAGE-first body with counted vmcnt(2) + raw barriers (no drain-0).
// Swapped QK^T; static-max softmax p=exp2(score); l-sum via ones-row MFMA;
// V sigma-permuted in global so PV A-fragments are single b128 LDS reads.
__global__ __launch_bounds__(512) void k_attn(
    const unsigned short* __restrict__ qb, const unsigned short* __restrict__ kb,
    const unsigned short* __restrict__ vt, float* __restrict__ out) {
  __shared__ unsigned short Kl[3][KVB * 64];  // [kv][d], 16B-chunk XOR-swizzled
  __shared__ unsigned short Vl[3][64 * KVB];  // [d][kv_sigma], XOR-swizzled
  const int tid = threadIdx.x;
  const int lane = tid & 63, wid = tid >> 6;
  const int ln = lane & 15, g = lane >> 4;
  const int flat = blockIdx.x;
  const int bh = flat & 63, qidx = flat >> 6;
  const int b = bh >> 4, h = bh & 15;
  const int q0 = qidx * 256 + wid * 32;
  const unsigned short* Qp = qb + (size_t)bh * SEQ * 64;
  const unsigned short* Kp = kb + (size_t)bh * SEQ * 64;
  const unsigned short* Vp = vt + (size_t)bh * 64 * SEQ;

  // staging source (per-thread, 16B-chunk XOR swizzle folded into global addr)
  const int kr0 = tid >> 3;
  const int psw = ((tid & 7) ^ (kr0 & 7)) << 3;
  const unsigned short* srcK0 = Kp + (size_t)kr0 * 64 + psw;
  const unsigned short* srcV0 = Vp + (size_t)kr0 * SEQ + psw;

#define STAGE(bb, tt)                                                     \
  do {                                                                    \
    gl_lds16(srcK0 + (size_t)(tt) * (KVB * 64), &Kl[bb][wid * 512]);      \
    gl_lds16(srcV0 + (size_t)(tt) * KVB, &Vl[bb][wid * 512]);             \
  } while (0)

  // Q fragments (one-time)
  u16x8 qf[2][2];
#pragma unroll
  for (int qt = 0; qt < 2; qt++)
#pragma unroll
    for (int dc = 0; dc < 2; dc++)
      qf[qt][dc] = *reinterpret_cast<const u16x8*>(
          &Qp[(size_t)(q0 + qt * 16 + ln) * 64 + dc * 32 + g * 8]);

  f32x4 o[4][2];
#pragma unroll
  for (int dt = 0; dt < 4; dt++)
#pragma unroll
    for (int qt = 0; qt < 2; qt++) o[dt][qt] = f32x4{0.f, 0.f, 0.f, 0.f};
  f32x4 lsum[2] = {f32x4{0.f, 0.f, 0.f, 0.f}, f32x4{0.f, 0.f, 0.f, 0.f}};

  u16x8 ones;
#pragma unroll
  for (int i = 0; i < 8; i++) ones[i] = 0x3F80;  // bf16 1.0

  // swizzled read offsets (elems)
  const int lm = ln & 7;
  const int ksw0 = (g ^ lm) << 3;
  const int ksw1 = ((4 + g) ^ lm) << 3;
  const int vsw0 = (g ^ lm) << 3;           // ks=0: chunk g
  const int vsw1 = ((4 + g) ^ lm) << 3;     // ks=1: chunk 4+g

#define ACOMPUTE(bi)                                                          \
  do {                                                                        \
    const unsigned short* Kb = Kl[bi];                                        \
    const unsigned short* Vb = Vl[bi];                                        \
    u16x8 kf[4][2];                                                           \
    _Pragma("unroll") for (int kt = 0; kt < 4; kt++) {                        \
      int rb = (kt * 16 + ln) * 64;                                           \
      kf[kt][0] = *reinterpret_cast<const u16x8*>(&Kb[rb + ksw0]);            \
      kf[kt][1] = *reinterpret_cast<const u16x8*>(&Kb[rb + ksw1]);            \
    }                                                                         \
    f32x4 st[2][4];                                                           \
    __builtin_amdgcn_s_setprio(1);                                            \
    _Pragma("unroll") for (int qt = 0; qt < 2; qt++)                          \
    _Pragma("unroll") for (int kt = 0; kt < 4; kt++) {                        \
      f32x4 c = f32x4{0.f, 0.f, 0.f, 0.f};                                    \
      c = mfma16(kf[kt][0], qf[qt][0], c);                                    \
      c = mfma16(kf[kt][1], qf[qt][1], c);                                    \
      st[qt][kt] = c;                                                         \
    }                                                                         \
    __builtin_amdgcn_s_setprio(0);                                            \
    _Pragma("unroll") for (int qt = 0; qt < 2; qt++)                          \
    _Pragma("unroll") for (int kt = 0; kt < 4; kt++)                          \
    _Pragma("unroll") for (int i = 0; i < 4; i++)                             \
      st[qt][kt][i] = EXP2(st[qt][kt][i]);                                    \
    bf16x8 pb[2][2];                                                          \
    _Pragma("unroll") for (int qt = 0; qt < 2; qt++)                          \
    _Pragma("unroll") for (int ks = 0; ks < 2; ks++)                          \
    _Pragma("unroll") for (int i = 0; i < 4; i++) {                           \
      pb[qt][ks][i] = (__bf16)st[qt][2 * ks][i];                              \
      pb[qt][ks][4 + i] = (__bf16)st[qt][2 * ks + 1][i];                      \
    }                                                                         \
    __builtin_amdgcn_s_setprio(1);                                            \
    _Pragma("unroll") for (int dt = 0; dt < 4; dt++) {                        \
      int rb = (dt * 16 + ln) * 64;                                           \
      u16x8 vf0 = *reinterpret_cast<const u16x8*>(&Vb[rb + vsw0]);            \
      o[dt][0] = mfma16b(vf0, pb[0][0], o[dt][0]);                            \
      o[dt][1] = mfma16b(vf0, pb[1][0], o[dt][1]);                            \
      u16x8 vf1 = *reinterpret_cast<const u16x8*>(&Vb[rb + vsw1]);            \
      o[dt][0] = mfma16b(vf1, pb[0][1], o[dt][0]);                            \
      o[dt][1] = mfma16b(vf1, pb[1][1], o[dt][1]);                            \
    }                                                                         \
    _Pragma("unroll") for (int ks = 0; ks < 2; ks++) {                        \
      lsum[0] = mfma16b(ones, pb[0][ks], lsum[0]);                            \
      lsum[1] = mfma16b(ones, pb[1][ks], lsum[1]);                            \
    }                                                                         \
    __builtin_amdgcn_s_setprio(0);                                            \
  } while (0)

  // prologue: 2 tiles in flight
  STAGE(0, 0);
  STAGE(1, 1);
  asm volatile("s_waitcnt vmcnt(2)" ::: "memory");   // tile 0 landed
  __builtin_amdgcn_s_barrier();

  for (int t = 0; t < NT - 2; t++) {
    STAGE((t + 2) % 3, t + 2);
    ACOMPUTE(t % 3);
    asm volatile("s_waitcnt vmcnt(2)" ::: "memory"); // tile t+1 landed
    __builtin_amdgcn_s_barrier();
  }
  ACOMPUTE((NT - 2) % 3);                            // tile 30
  asm volatile("s_waitcnt vmcnt(0)" ::: "memory");   // tile 31 landed
  __builtin_amdgcn_s_barrier();
  ACOMPUTE((NT - 1) % 3);                            // tile 31

  float inv[2] = {1.f / lsum[0][0], 1.f / lsum[1][0]};

#pragma unroll
  for (int qt = 0; qt < 2; qt++) {
    int q = q0 + qt * 16 + ln;
#pragma unroll
    for (int dt = 0; dt < 4; dt++) {
      f32x4 r;
#pragma unroll
      for (int i = 0; i < 4; i++) r[i] = o[dt][qt][i] * inv[qt];
      *reinterpret_cast<f32x4*>(
          &out[((size_t)(b * SEQ + q)) * 1024 + h * 64 + dt * 16 + 4 * g]) = r;
    }
  }
#undef STAGE
#undef ACOMPUTE
}

// ---------------- launch ----------------
extern "C" void kernel_launch(void* const* d_in, const int* in_sizes, int n_in,
                              void* d_out, int out_size, void* d_ws, size_t ws_size,
                              hipStream_t stream) {
  (void)in_sizes; (void)n_in; (void)out_size;
  const float* x  = (const float*)d_in[0];
  const float* Wq = (const float*)d_in[1];
  const float* bq = (const float*)d_in[2];
  const float* Wk = (const float*)d_in[3];
  const float* bk = (const float*)d_in[4];
  const float* Wv = (const float*)d_in[5];
  const float* bv = (const float*)d_in[6];
  float* out = (float*)d_out;

  char* ws = (char*)d_ws;
  // layout (bytes): xb 16MB | wt 6MB | q 16MB | k 16MB | vt 16MB  = 73400320
  if (ws_size < 73400320u) return;
  unsigned short* xb    = (unsigned short*)(ws);
  unsigned short* wt    = (unsigned short*)(ws + 16777216);
  unsigned short* qbuf  = (unsigned short*)(ws + 23068672);
  unsigned short* kbuf  = (unsigned short*)(ws + 39845888);
  unsigned short* vtbuf = (unsigned short*)(ws + 56623104);

  k_conv_x<<<4096, 256, 0, stream>>>(x, xb);
  k_conv_w<<<dim3(32, 32, 3), dim3(32, 8), 0, stream>>>(Wq, Wk, Wv, wt);
  k_qkv_gemm<<<dim3(1536), 256, 0, stream>>>(xb, wt, bq, bk, bv,
                                             qbuf, kbuf, vtbuf);
  k_attn<<<dim3(512), dim3(512), 0, stream>>>(qbuf, kbuf, vtbuf, out);
}